// Round 2
// baseline (548.685 us; speedup 1.0000x reference)
//
#include <hip/hip_runtime.h>
#include <hip/hip_bf16.h>

// Problem constants (B=2, N=2048, C=512, H=16, dh=32, topk=16)
#define NB 2
#define NN 2048
#define NC 512
#define NH 16
#define NDH 32
#define NROWS (NB * NN) // 4096
#define KTOP 16

#define SCALE 0.17677669529663687f    // 1/sqrt(32)
#define SCALE16 0.011048543456039804f // SCALE/16

typedef __attribute__((ext_vector_type(8))) short bf16x8;
typedef __attribute__((ext_vector_type(4))) float f32x4;

// ---------------------------------------------------------------------------
// K1/K2/K5: fp32 GEMM  C[M,N] = A[M,K] * B[N,K]^T  (+ epilogues), K = 512
// EPI 1: +bias, write f32 and bf16 copy for cols < 1024 (qkv projection)
// EPI 2: *SCALE16 + gumbel(noise)  (z = logits + gumbel); B rows per-batch
// EPI 3: *mean(head_scores) + bias (final projection)
// Tiles: 128x128, BK=16, 256 threads, 8x8 per thread.
// ---------------------------------------------------------------------------
template <int EPI>
__global__ __launch_bounds__(256, 2) void gemm_f32_kernel(
    const float* __restrict__ A, int lda, const float* __restrict__ Bm,
    int ldb, const float* __restrict__ bias, const float* __restrict__ noise,
    const float* __restrict__ hsp, float* __restrict__ Cc, int ldc,
    __hip_bfloat16* __restrict__ Cbf) {
  __shared__ float As[16][132];
  __shared__ float Bs[16][132];
  const int tid = threadIdx.x;
  const int bm = blockIdx.y * 128;
  const int bn = blockIdx.x * 128;
  const float* Bp = Bm;
  if constexpr (EPI == 2) Bp += (size_t)(bm >> 11) * (size_t)NN * ldb;
  const int tm = (tid >> 4) * 8;
  const int tn = (tid & 15) * 8;
  const int lrow = tid >> 2;      // 0..63
  const int lk4 = (tid & 3) * 4;  // 0,4,8,12
  const float* Ag = A + (size_t)(bm + lrow) * lda + lk4;
  const float* Bg = Bp + (size_t)(bn + lrow) * ldb + lk4;

  float acc[8][8] = {};
  for (int k0 = 0; k0 < 512; k0 += 16) {
    float4 av0 = *(const float4*)(Ag + k0);
    float4 av1 = *(const float4*)(Ag + (size_t)64 * lda + k0);
    float4 bv0 = *(const float4*)(Bg + k0);
    float4 bv1 = *(const float4*)(Bg + (size_t)64 * ldb + k0);
    __syncthreads();  // previous compute done before overwriting LDS
    As[lk4 + 0][lrow] = av0.x; As[lk4 + 1][lrow] = av0.y;
    As[lk4 + 2][lrow] = av0.z; As[lk4 + 3][lrow] = av0.w;
    As[lk4 + 0][lrow + 64] = av1.x; As[lk4 + 1][lrow + 64] = av1.y;
    As[lk4 + 2][lrow + 64] = av1.z; As[lk4 + 3][lrow + 64] = av1.w;
    Bs[lk4 + 0][lrow] = bv0.x; Bs[lk4 + 1][lrow] = bv0.y;
    Bs[lk4 + 2][lrow] = bv0.z; Bs[lk4 + 3][lrow] = bv0.w;
    Bs[lk4 + 0][lrow + 64] = bv1.x; Bs[lk4 + 1][lrow + 64] = bv1.y;
    Bs[lk4 + 2][lrow + 64] = bv1.z; Bs[lk4 + 3][lrow + 64] = bv1.w;
    __syncthreads();
#pragma unroll
    for (int k = 0; k < 16; k++) {
      float a[8], b[8];
      *(float4*)&a[0] = *(const float4*)&As[k][tm];
      *(float4*)&a[4] = *(const float4*)&As[k][tm + 4];
      *(float4*)&b[0] = *(const float4*)&Bs[k][tn];
      *(float4*)&b[4] = *(const float4*)&Bs[k][tn + 4];
#pragma unroll
      for (int i = 0; i < 8; i++)
#pragma unroll
        for (int j = 0; j < 8; j++) acc[i][j] = fmaf(a[i], b[j], acc[i][j]);
    }
  }

  float hs = 1.0f;
  if constexpr (EPI == 3) {
    float s = 0.f;
#pragma unroll
    for (int i = 0; i < NH; i++) s += hsp[i];
    hs = s * (1.0f / NH);
  }

#pragma unroll
  for (int i = 0; i < 8; i++) {
    const int row = bm + tm + i;
    float v[8];
#pragma unroll
    for (int j = 0; j < 8; j++) {
      const int col = bn + tn + j;
      float x = acc[i][j];
      if constexpr (EPI == 1) {
        x += bias[col];
      } else if constexpr (EPI == 2) {
        const int bb = row >> 11;
        const int n = row & (NN - 1);
        float u = noise[((size_t)bb << 22) + ((size_t)n << 11) + col];
        float g = -logf(-logf(u + 1e-9f) + 1e-9f);
        x = x * SCALE16 + g;
      } else {
        x = x * hs + bias[col];
      }
      v[j] = x;
    }
    float* cp = Cc + (size_t)row * ldc + bn + tn;
    *(float4*)&cp[0] = *(float4*)&v[0];
    *(float4*)&cp[4] = *(float4*)&v[4];
    if constexpr (EPI == 1) {
      const int col0 = bn + tn;
      if (col0 < 1024) {  // Q,K only; tile never straddles 1024
#pragma unroll
        for (int j = 0; j < 8; j++)
          Cbf[(size_t)row * 1024 + col0 + j] = __float2bfloat16(v[j]);
      }
    }
  }
}

// ---------------------------------------------------------------------------
// K3: per-row top-16 of z (with multiplicity, matching lax.top_k >= thresh),
// then write mask bitmap (64 bits per u64, 32 words per row).
// One block (256 threads) per row.
// ---------------------------------------------------------------------------
__global__ __launch_bounds__(256) void topk_kernel(
    const float* __restrict__ z, unsigned long long* __restrict__ mask,
    float* __restrict__ thresh) {
  const int row = blockIdx.x;
  const float* zr = z + (size_t)row * NN;
  __shared__ float ls[NN];
  __shared__ float wmax[4];
  __shared__ int widx[4];
  const int tid = threadIdx.x;
  const int lane = tid & 63;
  const int wv = tid >> 6;

  for (int i = tid; i < NN; i += 256) ls[i] = zr[i];
  __syncthreads();

  float last = 0.f;
  for (int it = 0; it < KTOP; it++) {
    float v = -INFINITY;
    int idx = -1;
#pragma unroll
    for (int i = tid; i < NN; i += 256) {
      float x = ls[i];
      if (x > v) { v = x; idx = i; }
    }
#pragma unroll
    for (int s = 1; s < 64; s <<= 1) {
      float ov = __shfl_xor(v, s);
      int oi = __shfl_xor(idx, s);
      if (ov > v || (ov == v && oi < idx)) { v = ov; idx = oi; }
    }
    if (lane == 0) { wmax[wv] = v; widx[wv] = idx; }
    __syncthreads();
    if (tid == 0) {
      float bv = wmax[0];
      int bi = widx[0];
      for (int w = 1; w < 4; w++)
        if (wmax[w] > bv || (wmax[w] == bv && widx[w] < bi)) {
          bv = wmax[w]; bi = widx[w];
        }
      ls[bi] = -INFINITY;  // exclude exactly one instance
      wmax[0] = bv;
    }
    __syncthreads();
    last = wmax[0];
    __syncthreads();
  }
  if (tid == 0) thresh[row] = last;

  // mask = (z >= last); re-read pristine z from global (L2/L3 resident)
  for (int i = tid; i < NN; i += 256) {
    unsigned long long bal = __ballot(zr[i] >= last);
    if (lane == 0) mask[(size_t)row * 32 + (i >> 6)] = bal;
  }
}

// ---------------------------------------------------------------------------
// K4: per (batch, head, 16-row wave): phase 1 = sum(exp(scores)) over the
// full row via MFMA bf16 16x16x32 (K=32=dh in one MFMA, no max needed since
// scores ~ N(0,1)); phase 2 = sparse gather over mask bits with fp32 q,k,v.
// Block = 4 waves = 64 rows. attn_out[row][h*32+d] = sum_m p*v.
// ---------------------------------------------------------------------------
__global__ __launch_bounds__(256) void attn_kernel(
    const float* __restrict__ qkv, const __hip_bfloat16* __restrict__ qkvbf,
    const unsigned long long* __restrict__ mask,
    float* __restrict__ attn_out) {
  const int lane = threadIdx.x & 63;
  const int wave = threadIdx.x >> 6;
  const int rowbase = blockIdx.x * 64 + wave * 16;
  const int h = blockIdx.y;
  const int b = rowbase >> 11;
  const int rl = lane & 15;
  const int g = lane >> 4;

  // ---- phase 1: denominators Z per row ----
  const short* qb = (const short*)qkvbf;
  bf16x8 afrag =
      *(const bf16x8*)&qb[(size_t)(rowbase + rl) * 1024 + h * NDH + g * 8];
  const short* kb = qb + (size_t)(b << 11) * 1024 + 512 + h * NDH + g * 8;
  float sum[4] = {0.f, 0.f, 0.f, 0.f};
  for (int m0 = 0; m0 < NN; m0 += 16) {
    bf16x8 bfrag = *(const bf16x8*)&kb[(size_t)(m0 + rl) * 1024];
    f32x4 zero = {0.f, 0.f, 0.f, 0.f};
    f32x4 d = __builtin_amdgcn_mfma_f32_16x16x32_bf16(afrag, bfrag, zero, 0, 0, 0);
    // lane holds S[row = g*4+j][col = m0+rl]
    sum[0] += __expf(d[0] * SCALE);
    sum[1] += __expf(d[1] * SCALE);
    sum[2] += __expf(d[2] * SCALE);
    sum[3] += __expf(d[3] * SCALE);
  }
#pragma unroll
  for (int j = 0; j < 4; j++)
#pragma unroll
    for (int s = 1; s < 16; s <<= 1) sum[j] += __shfl_xor(sum[j], s);

  __shared__ float Zs[4][16];
  if (rl == 0) {
#pragma unroll
    for (int j = 0; j < 4; j++) Zs[wave][g * 4 + j] = sum[j];
  }
  __syncthreads();

  // ---- phase 2: sparse gather. 4 lanes per row; lane 'slot' owns 8 chans.
  const int row_i = lane >> 2;
  const int slot = lane & 3;
  const int row = rowbase + row_i;
  const float Zinv = 1.0f / Zs[wave][row_i];
  const float* qrow = qkv + (size_t)row * 1536 + h * NDH + slot * 8;
  float q0[8];
  *(float4*)&q0[0] = *(const float4*)&qrow[0];
  *(float4*)&q0[4] = *(const float4*)&qrow[4];
  const float* Kf = qkv + (size_t)(b << 11) * 1536 + 512 + h * NDH + slot * 8;
  const float* Vf = qkv + (size_t)(b << 11) * 1536 + 1024 + h * NDH + slot * 8;
  float acc[8] = {};
  const unsigned long long* mrow = mask + (size_t)row * 32;
  for (int w = 0; w < 32; w++) {
    unsigned long long bits = mrow[w];
    while (bits) {
      const int t = __builtin_ctzll(bits);
      bits &= bits - 1;
      const int m = (w << 6) + t;
      const float* kr = Kf + (size_t)m * 1536;
      float kk[8];
      *(float4*)&kk[0] = *(const float4*)&kr[0];
      *(float4*)&kk[4] = *(const float4*)&kr[4];
      float part = 0.f;
#pragma unroll
      for (int d = 0; d < 8; d++) part = fmaf(q0[d], kk[d], part);
      part += __shfl_xor(part, 1);  // reduce across the 4 slots of this row
      part += __shfl_xor(part, 2);
      const float p = __expf(part * SCALE) * Zinv;
      const float* vr = Vf + (size_t)m * 1536;
      float vv[8];
      *(float4*)&vv[0] = *(const float4*)&vr[0];
      *(float4*)&vv[4] = *(const float4*)&vr[4];
#pragma unroll
      for (int d = 0; d < 8; d++) acc[d] = fmaf(p, vv[d], acc[d]);
    }
  }
  float* orow = attn_out + (size_t)row * NC + h * NDH + slot * 8;
  *(float4*)&orow[0] = *(float4*)&acc[0];
  *(float4*)&orow[4] = *(float4*)&acc[4];
}

// ---------------------------------------------------------------------------
extern "C" void kernel_launch(void* const* d_in, const int* in_sizes, int n_in,
                              void* d_out, int out_size, void* d_ws,
                              size_t ws_size, hipStream_t stream) {
  const float* value = (const float*)d_in[2];
  const float* noise = (const float*)d_in[4];
  const float* w_qkv = (const float*)d_in[5];
  const float* b_qkv = (const float*)d_in[6];
  const float* w_proj = (const float*)d_in[7];
  const float* b_proj = (const float*)d_in[8];
  const float* head_scores = (const float*)d_in[9];
  float* out = (float*)d_out;

  char* ws = (char*)d_ws;
  size_t o = 0;
  float* qkv = (float*)(ws + o);              o += (size_t)NROWS * 1536 * 4;  // 25.2 MB
  __hip_bfloat16* qkvbf = (__hip_bfloat16*)(ws + o); o += (size_t)NROWS * 1024 * 2; // 8.4 MB
  float* z = (float*)(ws + o);                o += (size_t)NROWS * NN * 4;    // 33.6 MB
  float* thr = (float*)(ws + o);              o += (size_t)NROWS * 4;
  unsigned long long* mask = (unsigned long long*)(ws + o); o += (size_t)NROWS * 32 * 8;
  float* attn_out = (float*)(ws + o);         o += (size_t)NROWS * NC * 4;    // 8.4 MB

  // K1: qkv = value @ w_qkv.T + b_qkv  (f32 + bf16 copy of Q,K)
  gemm_f32_kernel<1><<<dim3(1536 / 128, NROWS / 128), 256, 0, stream>>>(
      value, NC, w_qkv, NC, b_qkv, nullptr, nullptr, qkv, 1536, qkvbf);
  // K2: z = (scale/16) * Q @ K^T + gumbel(noise)
  gemm_f32_kernel<2><<<dim3(NN / 128, NROWS / 128), 256, 0, stream>>>(
      qkv, 1536, qkv + 512, 1536, nullptr, noise, nullptr, z, NN, nullptr);
  // K3: per-row top-16 threshold + mask bits
  topk_kernel<<<NROWS, 256, 0, stream>>>(z, mask, thr);
  // K4: per-head softmax denominators (MFMA) + sparse gather
  attn_kernel<<<dim3(NROWS / 64, NH), 256, 0, stream>>>(qkv, qkvbf, mask,
                                                        attn_out);
  // K5: out = (attn_out * mean(head_scores)) @ w_proj.T + b_proj
  gemm_f32_kernel<3><<<dim3(NC / 128, NROWS / 128), 256, 0, stream>>>(
      attn_out, NC, w_proj, NC, b_proj, nullptr, head_scores, out, NC,
      nullptr);
}

// Round 5
// 389.861 us; speedup vs baseline: 1.4074x; 1.4074x over previous
//
#include <hip/hip_runtime.h>
#include <hip/hip_bf16.h>

// Problem constants (B=2, N=2048, C=512, H=16, dh=32, topk=16)
#define NB 2
#define NN 2048
#define NC 512
#define NH 16
#define NDH 32
#define NROWS (NB * NN) // 4096
#define KTOP 16

#define SCALE 0.17677669529663687f    // 1/sqrt(32)
#define SCALE16 0.011048543456039804f // SCALE/16

typedef __attribute__((ext_vector_type(8))) short bf16x8;
typedef __attribute__((ext_vector_type(4))) float f32x4;

// async global->LDS, 16B per lane (dest must be linear: base + lane*16)
#define GLD16(g, l)                                                      \
  __builtin_amdgcn_global_load_lds(                                      \
      (const __attribute__((address_space(1))) void*)(g),                \
      (__attribute__((address_space(3))) void*)(l), 16, 0, 0)

// ---------------------------------------------------------------------------
// Split fp32 -> (hi|lo) bf16 rows: out[row][0..511]=hi, out[row][512..1023]=lo
// Covers value (4096x512), w_qkv (1536x512), w_proj (512x512).
// ---------------------------------------------------------------------------
__global__ __launch_bounds__(256) void split_kernel(
    const float* __restrict__ val, const float* __restrict__ wq,
    const float* __restrict__ wp, __hip_bfloat16* __restrict__ valsp,
    __hip_bfloat16* __restrict__ wqsp, __hip_bfloat16* __restrict__ wpsp) {
  const int row = blockIdx.x * 2 + (threadIdx.x >> 7);
  const int kc = (threadIdx.x & 127) * 4;
  const float* src;
  __hip_bfloat16* dst;
  int rr;
  if (row < 4096) {
    src = val; dst = valsp; rr = row;
  } else if (row < 5632) {
    src = wq; dst = wqsp; rr = row - 4096;
  } else {
    src = wp; dst = wpsp; rr = row - 5632;
  }
  float4 x = *(const float4*)&src[(size_t)rr * 512 + kc];
  float xs[4] = {x.x, x.y, x.z, x.w};
#pragma unroll
  for (int j = 0; j < 4; j++) {
    __hip_bfloat16 hi = __float2bfloat16(xs[j]);
    __hip_bfloat16 lo = __float2bfloat16(xs[j] - __bfloat162float(hi));
    dst[(size_t)rr * 1024 + kc + j] = hi;
    dst[(size_t)rr * 1024 + 512 + kc + j] = lo;
  }
}

// ---------------------------------------------------------------------------
// Split-bf16 MFMA GEMM: C[M,N] = A[M,K=512] * B[N,K=512]^T in 3 bf16 passes
// (hi*hi + hi*lo + lo*hi), operands stored as [hi(512)|lo(512)] bf16 rows.
// m97 structure: 128x128 tile, BK=64, 4 waves (2x2), global_load_lds w=16.
// EPI 1: +bias -> qkv f32 [M][1536]; also write hi/lo splits of Q,K cols.
// EPI 2: *SCALE16 + gumbel(noise) -> z  (B operand selected per batch)
// EPI 3: *mean(head_scores) + bias -> out
// ---------------------------------------------------------------------------
template <int EPI>
__global__ __launch_bounds__(256, 2) void gemm_bf16s(
    const __hip_bfloat16* __restrict__ Aspg, int lda,
    const __hip_bfloat16* __restrict__ Bspg, int ldb,
    const float* __restrict__ bias, const float* __restrict__ noise,
    const float* __restrict__ hsp, float* __restrict__ Cc, int ldc,
    float* __restrict__ qkvf, __hip_bfloat16* __restrict__ Qsp,
    __hip_bfloat16* __restrict__ Ksp) {
  __shared__ short As[128 * 64];
  __shared__ short Bs[128 * 64];
  const int t = threadIdx.x;
  const int lane = t & 63;
  const int wv = t >> 6;
  const int wr = wv >> 1, wc = wv & 1;  // 2x2 wave grid, 64x64 per wave
  const int bm = blockIdx.y * 128;
  const int bn = blockIdx.x * 128;
  const short* Asp = (const short*)Aspg;
  const short* Bsp = (const short*)Bspg;
  if constexpr (EPI == 2) Bsp += (size_t)(bm >> 11) * 2048 * (size_t)ldb;

  const int r = lane & 15, g = lane >> 4;
  const int srow = t >> 3;         // staging row within 32-row group
  const int scol = (t & 7) * 8;    // staging col (elements)

  f32x4 acc[4][4];
#pragma unroll
  for (int m = 0; m < 4; m++)
#pragma unroll
    for (int n = 0; n < 4; n++) acc[m][n] = {0.f, 0.f, 0.f, 0.f};

  for (int s = 0; s < 24; s++) {
    const int pass = s >> 3;
    const int k0 = (s & 7) * 64;
    const int aoff = (pass == 2) ? 512 : 0;
    const int boff = (pass == 1) ? 512 : 0;
    __syncthreads();  // previous compute done before LDS overwrite
#pragma unroll
    for (int i = 0; i < 4; i++) {
      GLD16(Asp + (size_t)(bm + i * 32 + srow) * lda + aoff + k0 + scol,
            &As[i * 2048 + t * 8]);
      GLD16(Bsp + (size_t)(bn + i * 32 + srow) * ldb + boff + k0 + scol,
            &Bs[i * 2048 + t * 8]);
    }
    __syncthreads();  // staging drained (compiler emits vmcnt(0) before barrier)
    bf16x8 af[4][2], bfr[4][2];
#pragma unroll
    for (int m = 0; m < 4; m++)
#pragma unroll
      for (int ks = 0; ks < 2; ks++)
        af[m][ks] =
            *(const bf16x8*)&As[(wr * 64 + m * 16 + r) * 64 + ks * 32 + g * 8];
#pragma unroll
    for (int n = 0; n < 4; n++)
#pragma unroll
      for (int ks = 0; ks < 2; ks++)
        bfr[n][ks] =
            *(const bf16x8*)&Bs[(wc * 64 + n * 16 + r) * 64 + ks * 32 + g * 8];
#pragma unroll
    for (int m = 0; m < 4; m++)
#pragma unroll
      for (int n = 0; n < 4; n++) {
        acc[m][n] = __builtin_amdgcn_mfma_f32_16x16x32_bf16(
            af[m][0], bfr[n][0], acc[m][n], 0, 0, 0);
        acc[m][n] = __builtin_amdgcn_mfma_f32_16x16x32_bf16(
            af[m][1], bfr[n][1], acc[m][n], 0, 0, 0);
      }
  }

  float hs = 1.0f;
  if constexpr (EPI == 3) {
    float ssum = 0.f;
#pragma unroll
    for (int i = 0; i < NH; i++) ssum += hsp[i];
    hs = ssum * (1.0f / NH);
  }

  // C/D layout (m89-verified): col = lane&15, row = (lane>>4)*4 + reg
#pragma unroll
  for (int m = 0; m < 4; m++)
#pragma unroll
    for (int n = 0; n < 4; n++)
#pragma unroll
      for (int j = 0; j < 4; j++) {
        const int row = bm + wr * 64 + m * 16 + g * 4 + j;
        const int col = bn + wc * 64 + n * 16 + r;
        float x = acc[m][n][j];
        if constexpr (EPI == 1) {
          x += bias[col];
          qkvf[(size_t)row * 1536 + col] = x;
          if (col < 1024) {  // Q,K: write hi/lo split for K2
            __hip_bfloat16 hi = __float2bfloat16(x);
            __hip_bfloat16 lo = __float2bfloat16(x - __bfloat162float(hi));
            __hip_bfloat16* dst = (col < 512) ? Qsp : Ksp;
            const int c = col & 511;
            dst[(size_t)row * 1024 + c] = hi;
            dst[(size_t)row * 1024 + c + 512] = lo;
          }
        } else if constexpr (EPI == 2) {
          const int bb = row >> 11;
          const int nr = row & (NN - 1);
          float u = noise[((size_t)bb << 22) + ((size_t)nr << 11) + col];
          float gum = -logf(-logf(u + 1e-9f) + 1e-9f);
          Cc[(size_t)row * ldc + col] = x * SCALE16 + gum;
        } else {
          Cc[(size_t)row * ldc + col] = x * hs + bias[col];
        }
      }
}

// ---------------------------------------------------------------------------
// K3: per-row top-16 of z (with multiplicity), mask bitmap out.
// One block (256 threads) per row.
// ---------------------------------------------------------------------------
__global__ __launch_bounds__(256) void topk_kernel(
    const float* __restrict__ z, unsigned long long* __restrict__ mask,
    float* __restrict__ thresh) {
  const int row = blockIdx.x;
  const float* zr = z + (size_t)row * NN;
  __shared__ float ls[NN];
  __shared__ float wmax[4];
  __shared__ int widx[4];
  const int tid = threadIdx.x;
  const int lane = tid & 63;
  const int wv = tid >> 6;

  for (int i = tid; i < NN; i += 256) ls[i] = zr[i];
  __syncthreads();

  float last = 0.f;
  for (int it = 0; it < KTOP; it++) {
    float v = -INFINITY;
    int idx = -1;
#pragma unroll
    for (int i = tid; i < NN; i += 256) {
      float x = ls[i];
      if (x > v) { v = x; idx = i; }
    }
#pragma unroll
    for (int s = 1; s < 64; s <<= 1) {
      float ov = __shfl_xor(v, s);
      int oi = __shfl_xor(idx, s);
      if (ov > v || (ov == v && oi < idx)) { v = ov; idx = oi; }
    }
    if (lane == 0) { wmax[wv] = v; widx[wv] = idx; }
    __syncthreads();
    if (tid == 0) {
      float bv = wmax[0];
      int bi = widx[0];
      for (int w = 1; w < 4; w++)
        if (wmax[w] > bv || (wmax[w] == bv && widx[w] < bi)) {
          bv = wmax[w]; bi = widx[w];
        }
      ls[bi] = -INFINITY;  // exclude exactly one instance
      wmax[0] = bv;
    }
    __syncthreads();
    last = wmax[0];
    __syncthreads();
  }
  if (tid == 0) thresh[row] = last;

  for (int i = tid; i < NN; i += 256) {
    unsigned long long bal = __ballot(zr[i] >= last);
    if (lane == 0) mask[(size_t)row * 32 + (i >> 6)] = bal;
  }
}

// ---------------------------------------------------------------------------
// K4: phase 1 = per-head softmax denominators via MFMA over bf16 hi parts;
// phase 2 = sparse fp32 gather over mask bits. Writes hi/lo split attn_out.
// ---------------------------------------------------------------------------
__global__ __launch_bounds__(256) void attn_kernel(
    const float* __restrict__ qkv, const __hip_bfloat16* __restrict__ Qsp,
    const __hip_bfloat16* __restrict__ Ksp,
    const unsigned long long* __restrict__ mask,
    __hip_bfloat16* __restrict__ aosp) {
  const int lane = threadIdx.x & 63;
  const int wave = threadIdx.x >> 6;
  const int rowbase = blockIdx.x * 64 + wave * 16;
  const int h = blockIdx.y;
  const int b = rowbase >> 11;
  const int rl = lane & 15;
  const int g = lane >> 4;

  // ---- phase 1: denominators Z per row (bf16 hi parts, fp32 accum) ----
  const short* qb = (const short*)Qsp;
  bf16x8 afrag =
      *(const bf16x8*)&qb[(size_t)(rowbase + rl) * 1024 + h * NDH + g * 8];
  const short* kb =
      (const short*)Ksp + (size_t)(b << 11) * 1024 + h * NDH + g * 8;
  float sum[4] = {0.f, 0.f, 0.f, 0.f};
  for (int m0 = 0; m0 < NN; m0 += 16) {
    bf16x8 bfrag = *(const bf16x8*)&kb[(size_t)(m0 + rl) * 1024];
    f32x4 zero = {0.f, 0.f, 0.f, 0.f};
    f32x4 d =
        __builtin_amdgcn_mfma_f32_16x16x32_bf16(afrag, bfrag, zero, 0, 0, 0);
    sum[0] += __expf(d[0] * SCALE);
    sum[1] += __expf(d[1] * SCALE);
    sum[2] += __expf(d[2] * SCALE);
    sum[3] += __expf(d[3] * SCALE);
  }
#pragma unroll
  for (int j = 0; j < 4; j++)
#pragma unroll
    for (int s = 1; s < 16; s <<= 1) sum[j] += __shfl_xor(sum[j], s);

  __shared__ float Zs[4][16];
  if (rl == 0) {
#pragma unroll
    for (int j = 0; j < 4; j++) Zs[wave][g * 4 + j] = sum[j];
  }
  __syncthreads();

  // ---- phase 2: sparse gather. 4 lanes per row; lane 'slot' owns 8 chans.
  const int row_i = lane >> 2;
  const int slot = lane & 3;
  const int row = rowbase + row_i;
  const float Zinv = 1.0f / Zs[wave][row_i];
  const float* qrow = qkv + (size_t)row * 1536 + h * NDH + slot * 8;
  float q0[8];
  *(float4*)&q0[0] = *(const float4*)&qrow[0];
  *(float4*)&q0[4] = *(const float4*)&qrow[4];
  const float* Kf = qkv + (size_t)(b << 11) * 1536 + 512 + h * NDH + slot * 8;
  const float* Vf = qkv + (size_t)(b << 11) * 1536 + 1024 + h * NDH + slot * 8;
  float acc[8] = {};
  const unsigned long long* mrow = mask + (size_t)row * 32;
  for (int w = 0; w < 32; w++) {
    unsigned long long bits = mrow[w];
    while (bits) {
      const int t = __builtin_ctzll(bits);
      bits &= bits - 1;
      const int m = (w << 6) + t;
      const float* kr = Kf + (size_t)m * 1536;
      float kk[8];
      *(float4*)&kk[0] = *(const float4*)&kr[0];
      *(float4*)&kk[4] = *(const float4*)&kr[4];
      float part = 0.f;
#pragma unroll
      for (int d = 0; d < 8; d++) part = fmaf(q0[d], kk[d], part);
      part += __shfl_xor(part, 1);
      part += __shfl_xor(part, 2);
      const float p = __expf(part * SCALE) * Zinv;
      const float* vr = Vf + (size_t)m * 1536;
      float vv[8];
      *(float4*)&vv[0] = *(const float4*)&vr[0];
      *(float4*)&vv[4] = *(const float4*)&vr[4];
#pragma unroll
      for (int d = 0; d < 8; d++) acc[d] = fmaf(p, vv[d], acc[d]);
    }
  }
  // write hi/lo split of attn_out for K5's MFMA A-operand
#pragma unroll
  for (int d = 0; d < 8; d++) {
    __hip_bfloat16 hi = __float2bfloat16(acc[d]);
    __hip_bfloat16 lo = __float2bfloat16(acc[d] - __bfloat162float(hi));
    aosp[(size_t)row * 1024 + h * NDH + slot * 8 + d] = hi;
    aosp[(size_t)row * 1024 + 512 + h * NDH + slot * 8 + d] = lo;
  }
}

// ---------------------------------------------------------------------------
extern "C" void kernel_launch(void* const* d_in, const int* in_sizes, int n_in,
                              void* d_out, int out_size, void* d_ws,
                              size_t ws_size, hipStream_t stream) {
  const float* value = (const float*)d_in[2];
  const float* noise = (const float*)d_in[4];
  const float* w_qkv = (const float*)d_in[5];
  const float* b_qkv = (const float*)d_in[6];
  const float* w_proj = (const float*)d_in[7];
  const float* b_proj = (const float*)d_in[8];
  const float* head_scores = (const float*)d_in[9];
  float* out = (float*)d_out;

  char* ws = (char*)d_ws;
  size_t o = 0;
  float* qkv = (float*)(ws + o);                 o += (size_t)NROWS * 1536 * 4;  // 25.2 MB
  __hip_bfloat16* Qsp = (__hip_bfloat16*)(ws + o); o += (size_t)NROWS * 1024 * 2; // 8.4 MB
  __hip_bfloat16* Ksp = (__hip_bfloat16*)(ws + o); o += (size_t)NROWS * 1024 * 2; // 8.4 MB
  __hip_bfloat16* wpsp = (__hip_bfloat16*)(ws + o); o += (size_t)512 * 1024 * 2;  // 1.0 MB
  float* thr = (float*)(ws + o);                 o += (size_t)NROWS * 4;
  unsigned long long* mask = (unsigned long long*)(ws + o); o += (size_t)NROWS * 32 * 8;
  __hip_bfloat16* aosp = (__hip_bfloat16*)(ws + o); o += (size_t)NROWS * 1024 * 2; // 8.4 MB
  float* z = (float*)(ws + o);                   o += (size_t)NROWS * NN * 4;    // 33.6 MB
  // valsp/wqsp alias z: dead before K2 writes z
  __hip_bfloat16* valsp = (__hip_bfloat16*)z;                       // 8.4 MB
  __hip_bfloat16* wqsp = (__hip_bfloat16*)((char*)z + 8388608);     // 3.1 MB

  // K0: split value / w_qkv / w_proj into (hi|lo) bf16 rows
  split_kernel<<<3072, 256, 0, stream>>>(value, w_qkv, w_proj, valsp, wqsp,
                                         wpsp);
  // K1: qkv = value @ w_qkv.T + b_qkv  (f32 qkv + Q,K hi/lo splits)
  gemm_bf16s<1><<<dim3(12, 32), 256, 0, stream>>>(
      valsp, 1024, wqsp, 1024, b_qkv, nullptr, nullptr, nullptr, 0, qkv, Qsp,
      Ksp);
  // K2: z = (scale/16) * Q @ K^T + gumbel(noise)
  gemm_bf16s<2><<<dim3(16, 32), 256, 0, stream>>>(
      Qsp, 1024, Ksp, 1024, nullptr, noise, nullptr, z, NN, nullptr, nullptr,
      nullptr);
  // K3: per-row top-16 threshold + mask bits
  topk_kernel<<<NROWS, 256, 0, stream>>>(z, mask, thr);
  // K4: denominators (MFMA) + sparse gather -> attn_out hi/lo split
  attn_kernel<<<dim3(NROWS / 64, NH), 256, 0, stream>>>(qkv, Qsp, Ksp, mask,
                                                        aosp);
  // K5: out = (attn_out * mean(head_scores)) @ w_proj.T + b_proj
  gemm_bf16s<3><<<dim3(4, 32), 256, 0, stream>>>(
      aosp, 1024, wpsp, 1024, b_proj, nullptr, head_scores, out, NC, nullptr,
      nullptr, nullptr);
}

// Round 6
// 362.318 us; speedup vs baseline: 1.5144x; 1.0760x over previous
//
#include <hip/hip_runtime.h>
#include <hip/hip_bf16.h>

// Problem constants (B=2, N=2048, C=512, H=16, dh=32, topk=16)
#define NB 2
#define NN 2048
#define NC 512
#define NH 16
#define NDH 32
#define NROWS (NB * NN) // 4096
#define KTOP 16

#define SCALE 0.17677669529663687f    // 1/sqrt(32)
#define SCALE16 0.011048543456039804f // SCALE/16

typedef __attribute__((ext_vector_type(8))) short bf16x8;
typedef __attribute__((ext_vector_type(4))) float f32x4;

// async global->LDS, 16B per lane (dest must be linear: base + lane*16)
#define GLD16(g, l)                                                      \
  __builtin_amdgcn_global_load_lds(                                      \
      (const __attribute__((address_space(1))) void*)(g),                \
      (__attribute__((address_space(3))) void*)(l), 16, 0, 0)

// ---------------------------------------------------------------------------
// Split fp32 -> (hi|lo) bf16 rows: out[row][0..511]=hi, out[row][512..1023]=lo
// ---------------------------------------------------------------------------
__global__ __launch_bounds__(256) void split_kernel(
    const float* __restrict__ val, const float* __restrict__ wq,
    const float* __restrict__ wp, __hip_bfloat16* __restrict__ valsp,
    __hip_bfloat16* __restrict__ wqsp, __hip_bfloat16* __restrict__ wpsp) {
  const int row = blockIdx.x * 2 + (threadIdx.x >> 7);
  const int kc = (threadIdx.x & 127) * 4;
  const float* src;
  __hip_bfloat16* dst;
  int rr;
  if (row < 4096) {
    src = val; dst = valsp; rr = row;
  } else if (row < 5632) {
    src = wq; dst = wqsp; rr = row - 4096;
  } else {
    src = wp; dst = wpsp; rr = row - 5632;
  }
  float4 x = *(const float4*)&src[(size_t)rr * 512 + kc];
  float xs[4] = {x.x, x.y, x.z, x.w};
#pragma unroll
  for (int j = 0; j < 4; j++) {
    __hip_bfloat16 hi = __float2bfloat16(xs[j]);
    __hip_bfloat16 lo = __float2bfloat16(xs[j] - __bfloat162float(hi));
    dst[(size_t)rr * 1024 + kc + j] = hi;
    dst[(size_t)rr * 1024 + 512 + kc + j] = lo;
  }
}

// ---------------------------------------------------------------------------
// Split-bf16 MFMA GEMM (3 passes: hi*hi + hi*lo + lo*hi), 128x128 tile, BK=64.
// EPI 1: +bias -> qkv f32; Q,K hi/lo splits; head-major K-hi copy (Khm).
// EPI 2: *SCALE16 + gumbel(noise) -> z
// EPI 3: *mean(head_scores) + bias -> out
// ---------------------------------------------------------------------------
template <int EPI>
__global__ __launch_bounds__(256, 2) void gemm_bf16s(
    const __hip_bfloat16* __restrict__ Aspg, int lda,
    const __hip_bfloat16* __restrict__ Bspg, int ldb,
    const float* __restrict__ bias, const float* __restrict__ noise,
    const float* __restrict__ hsp, float* __restrict__ Cc, int ldc,
    float* __restrict__ qkvf, __hip_bfloat16* __restrict__ Qsp,
    __hip_bfloat16* __restrict__ Ksp, __hip_bfloat16* __restrict__ Khm) {
  __shared__ short As[128 * 64];
  __shared__ short Bs[128 * 64];
  const int t = threadIdx.x;
  const int lane = t & 63;
  const int wv = t >> 6;
  const int wr = wv >> 1, wc = wv & 1;  // 2x2 wave grid, 64x64 per wave
  const int bm = blockIdx.y * 128;
  const int bn = blockIdx.x * 128;
  const short* Asp = (const short*)Aspg;
  const short* Bsp = (const short*)Bspg;
  if constexpr (EPI == 2) Bsp += (size_t)(bm >> 11) * 2048 * (size_t)ldb;

  const int r = lane & 15, g = lane >> 4;
  const int srow = t >> 3;       // staging row within 32-row group
  const int scol = (t & 7) * 8;  // staging col (elements)

  f32x4 acc[4][4];
#pragma unroll
  for (int m = 0; m < 4; m++)
#pragma unroll
    for (int n = 0; n < 4; n++) acc[m][n] = {0.f, 0.f, 0.f, 0.f};

  for (int s = 0; s < 24; s++) {
    const int pass = s >> 3;
    const int k0 = (s & 7) * 64;
    const int aoff = (pass == 2) ? 512 : 0;
    const int boff = (pass == 1) ? 512 : 0;
    __syncthreads();  // previous compute done before LDS overwrite
#pragma unroll
    for (int i = 0; i < 4; i++) {
      GLD16(Asp + (size_t)(bm + i * 32 + srow) * lda + aoff + k0 + scol,
            &As[i * 2048 + t * 8]);
      GLD16(Bsp + (size_t)(bn + i * 32 + srow) * ldb + boff + k0 + scol,
            &Bs[i * 2048 + t * 8]);
    }
    __syncthreads();  // staging drained
    bf16x8 af[4][2], bfr[4][2];
#pragma unroll
    for (int m = 0; m < 4; m++)
#pragma unroll
      for (int ks = 0; ks < 2; ks++)
        af[m][ks] =
            *(const bf16x8*)&As[(wr * 64 + m * 16 + r) * 64 + ks * 32 + g * 8];
#pragma unroll
    for (int n = 0; n < 4; n++)
#pragma unroll
      for (int ks = 0; ks < 2; ks++)
        bfr[n][ks] =
            *(const bf16x8*)&Bs[(wc * 64 + n * 16 + r) * 64 + ks * 32 + g * 8];
#pragma unroll
    for (int m = 0; m < 4; m++)
#pragma unroll
      for (int n = 0; n < 4; n++) {
        acc[m][n] = __builtin_amdgcn_mfma_f32_16x16x32_bf16(
            af[m][0], bfr[n][0], acc[m][n], 0, 0, 0);
        acc[m][n] = __builtin_amdgcn_mfma_f32_16x16x32_bf16(
            af[m][1], bfr[n][1], acc[m][n], 0, 0, 0);
      }
  }

  float hs = 1.0f;
  if constexpr (EPI == 3) {
    float ssum = 0.f;
#pragma unroll
    for (int i = 0; i < NH; i++) ssum += hsp[i];
    hs = ssum * (1.0f / NH);
  }

  // C/D layout (m89-verified): col = lane&15, row = (lane>>4)*4 + reg
#pragma unroll
  for (int m = 0; m < 4; m++)
#pragma unroll
    for (int n = 0; n < 4; n++)
#pragma unroll
      for (int j = 0; j < 4; j++) {
        const int row = bm + wr * 64 + m * 16 + g * 4 + j;
        const int col = bn + wc * 64 + n * 16 + r;
        float x = acc[m][n][j];
        if constexpr (EPI == 1) {
          x += bias[col];
          qkvf[(size_t)row * 1536 + col] = x;
          if (col < 1024) {  // Q,K: hi/lo split for K2
            __hip_bfloat16 hi = __float2bfloat16(x);
            __hip_bfloat16 lo = __float2bfloat16(x - __bfloat162float(hi));
            __hip_bfloat16* dst = (col < 512) ? Qsp : Ksp;
            const int c = col & 511;
            dst[(size_t)row * 1024 + c] = hi;
            dst[(size_t)row * 1024 + c + 512] = lo;
            if (col >= 512) {  // head-major K-hi for denom kernel
              const int kc = col - 512;
              Khm[((size_t)(kc >> 5) * NROWS + row) * NDH + (kc & 31)] = hi;
            }
          }
        } else if constexpr (EPI == 2) {
          const int bb = row >> 11;
          const int nr = row & (NN - 1);
          float u = noise[((size_t)bb << 22) + ((size_t)nr << 11) + col];
          float gum = -logf(-logf(u + 1e-9f) + 1e-9f);
          Cc[(size_t)row * ldc + col] = x * SCALE16 + gum;
        } else {
          Cc[(size_t)row * ldc + col] = x * hs + bias[col];
        }
      }
}

// ---------------------------------------------------------------------------
// K3: per-row top-16 of z (with multiplicity), mask bitmap out.
// ---------------------------------------------------------------------------
__global__ __launch_bounds__(256) void topk_kernel(
    const float* __restrict__ z, unsigned long long* __restrict__ mask,
    float* __restrict__ thresh) {
  const int row = blockIdx.x;
  const float* zr = z + (size_t)row * NN;
  __shared__ float ls[NN];
  __shared__ float wmax[4];
  __shared__ int widx[4];
  const int tid = threadIdx.x;
  const int lane = tid & 63;
  const int wv = tid >> 6;

  for (int i = tid; i < NN; i += 256) ls[i] = zr[i];
  __syncthreads();

  float last = 0.f;
  for (int it = 0; it < KTOP; it++) {
    float v = -INFINITY;
    int idx = -1;
#pragma unroll
    for (int i = tid; i < NN; i += 256) {
      float x = ls[i];
      if (x > v) { v = x; idx = i; }
    }
#pragma unroll
    for (int s = 1; s < 64; s <<= 1) {
      float ov = __shfl_xor(v, s);
      int oi = __shfl_xor(idx, s);
      if (ov > v || (ov == v && oi < idx)) { v = ov; idx = oi; }
    }
    if (lane == 0) { wmax[wv] = v; widx[wv] = idx; }
    __syncthreads();
    if (tid == 0) {
      float bv = wmax[0];
      int bi = widx[0];
      for (int w = 1; w < 4; w++)
        if (wmax[w] > bv || (wmax[w] == bv && widx[w] < bi)) {
          bv = wmax[w]; bi = widx[w];
        }
      ls[bi] = -INFINITY;  // exclude exactly one instance
      wmax[0] = bv;
    }
    __syncthreads();
    last = wmax[0];
    __syncthreads();
  }
  if (tid == 0) thresh[row] = last;

  for (int i = tid; i < NN; i += 256) {
    unsigned long long bal = __ballot(zr[i] >= last);
    if (lane == 0) mask[(size_t)row * 32 + (i >> 6)] = bal;
  }
}

// ---------------------------------------------------------------------------
// K4a: per-head softmax denominators via MFMA over head-major K-hi.
// Grid (64 rowgroups, 16 heads, 2 kv-chunks); wave = 16 Q-rows; no LDS.
// Writes Zpart[chunk][row][head] (two-part deterministic sum).
// ---------------------------------------------------------------------------
__global__ __launch_bounds__(256) void denom_kernel(
    const __hip_bfloat16* __restrict__ Qsp, const __hip_bfloat16* __restrict__ Khm,
    float* __restrict__ Zpart) {
  const int lane = threadIdx.x & 63;
  const int wave = threadIdx.x >> 6;
  const int rowbase = blockIdx.x * 64 + wave * 16;
  const int h = blockIdx.y;
  const int chunk = blockIdx.z;
  const int b = rowbase >> 11;
  const int rl = lane & 15;
  const int g = lane >> 4;

  const short* qb = (const short*)Qsp;
  bf16x8 afrag =
      *(const bf16x8*)&qb[(size_t)(rowbase + rl) * 1024 + h * NDH + g * 8];
  // head-major K-hi: contiguous [row][32ch] rows for this head
  const short* kb = (const short*)Khm +
                    ((size_t)h * NROWS + (b << 11) + chunk * 1024) * NDH;
  float sum[4] = {0.f, 0.f, 0.f, 0.f};
  for (int m0 = 0; m0 < 1024; m0 += 32) {
    bf16x8 b0 = *(const bf16x8*)&kb[(m0 + rl) * NDH + g * 8];
    bf16x8 b1 = *(const bf16x8*)&kb[(m0 + 16 + rl) * NDH + g * 8];
    f32x4 zero = {0.f, 0.f, 0.f, 0.f};
    f32x4 d0 =
        __builtin_amdgcn_mfma_f32_16x16x32_bf16(afrag, b0, zero, 0, 0, 0);
    f32x4 d1 =
        __builtin_amdgcn_mfma_f32_16x16x32_bf16(afrag, b1, zero, 0, 0, 0);
#pragma unroll
    for (int j = 0; j < 4; j++)
      sum[j] += __expf(d0[j] * SCALE) + __expf(d1[j] * SCALE);
  }
#pragma unroll
  for (int j = 0; j < 4; j++)
#pragma unroll
    for (int s = 1; s < 16; s <<= 1) sum[j] += __shfl_xor(sum[j], s);
  if (rl == 0) {
#pragma unroll
    for (int j = 0; j < 4; j++) {
      const int row = rowbase + g * 4 + j;
      Zpart[((size_t)chunk << 16) + (size_t)row * NH + h] = sum[j];
    }
  }
}

// ---------------------------------------------------------------------------
// K4b: sparse gather, all hits in parallel. Wave = 2 rows x 1 head; per row
// 32 lanes: collect hit indices (ballot prefix-scan -> LDS), then 2 lanes/hit
// x 16 ch process up to 16 hits concurrently. Writes hi/lo split attn_out.
// ---------------------------------------------------------------------------
__global__ __launch_bounds__(256) void gather_kernel(
    const float* __restrict__ qkv, const float* __restrict__ Zpart,
    const unsigned long long* __restrict__ mask,
    __hip_bfloat16* __restrict__ aosp) {
  const int t = threadIdx.x;
  const int lane = t & 63;
  const int wave = t >> 6;
  const int l32 = lane & 31;
  const int rhalf = lane >> 5;
  const int row = blockIdx.x * 8 + wave * 2 + rhalf;
  const int h = blockIdx.y;
  const int b = row >> 11;
  const int rloc = wave * 2 + rhalf;

  __shared__ int idxbuf[8][64];
  __shared__ int cnts[8];

  // ---- collect hit indices: lane l32 scans mask word l32 ----
  const unsigned long long* mrow = mask + (size_t)row * 32;
  unsigned long long bits = mrow[l32];
  int c = __popcll(bits);
  int p = c;
#pragma unroll
  for (int d = 1; d < 32; d <<= 1) {
    int o = __shfl_up(p, d, 32);
    if (l32 >= d) p += o;
  }
  int total = __shfl(p, 31, 32);
  p -= c;  // exclusive prefix
  while (bits) {
    int tz = __builtin_ctzll(bits);
    bits &= bits - 1;
    if (p < 64) idxbuf[rloc][p] = (l32 << 6) + tz;
    p++;
  }
  if (l32 == 0) cnts[rloc] = total > 64 ? 64 : total;
  __syncthreads();
  const int cnt = cnts[rloc];

  // ---- parallel gather: 2 lanes per hit, 16 channels per lane ----
  const int chb = h * NDH + (l32 & 1) * 16;
  const float* qrow = qkv + (size_t)row * 1536 + chb;
  float q0[16];
#pragma unroll
  for (int i = 0; i < 4; i++)
    *(float4*)&q0[i * 4] = *(const float4*)&qrow[i * 4];
  const float* Kf = qkv + (size_t)(b << 11) * 1536 + 512 + chb;
  const float* Vf = qkv + (size_t)(b << 11) * 1536 + 1024 + chb;
  float acc[16] = {};
  for (int base = 0; base < cnt; base += 16) {
    const int hit = base + (l32 >> 1);
    const bool valid = hit < cnt;
    const int m = valid ? idxbuf[rloc][hit] : 0;
    const float* kr = Kf + (size_t)m * 1536;
    float part = 0.f;
#pragma unroll
    for (int i = 0; i < 4; i++) {
      float4 kv4 = *(const float4*)&kr[i * 4];
      part = fmaf(q0[i * 4 + 0], kv4.x, part);
      part = fmaf(q0[i * 4 + 1], kv4.y, part);
      part = fmaf(q0[i * 4 + 2], kv4.z, part);
      part = fmaf(q0[i * 4 + 3], kv4.w, part);
    }
    part += __shfl_xor(part, 1);  // combine the channel-halves of this hit
    const float pexp = valid ? __expf(part * SCALE) : 0.f;
    const float* vr = Vf + (size_t)m * 1536;
#pragma unroll
    for (int i = 0; i < 4; i++) {
      float4 vv4 = *(const float4*)&vr[i * 4];
      acc[i * 4 + 0] = fmaf(pexp, vv4.x, acc[i * 4 + 0]);
      acc[i * 4 + 1] = fmaf(pexp, vv4.y, acc[i * 4 + 1]);
      acc[i * 4 + 2] = fmaf(pexp, vv4.z, acc[i * 4 + 2]);
      acc[i * 4 + 3] = fmaf(pexp, vv4.w, acc[i * 4 + 3]);
    }
  }
  // sum across the 16 hit-pairs (keeps channel-half split on bit 0)
#pragma unroll
  for (int s = 2; s < 32; s <<= 1)
#pragma unroll
    for (int ch = 0; ch < 16; ch++) acc[ch] += __shfl_xor(acc[ch], s);

  if (l32 < 2) {
    const float Z = Zpart[(size_t)row * NH + h] +
                    Zpart[(1 << 16) + (size_t)row * NH + h];
    const float Zinv = 1.0f / Z;
#pragma unroll
    for (int ch = 0; ch < 16; ch++) {
      const float v = acc[ch] * Zinv;
      __hip_bfloat16 hi = __float2bfloat16(v);
      __hip_bfloat16 lo = __float2bfloat16(v - __bfloat162float(hi));
      aosp[(size_t)row * 1024 + chb + ch] = hi;
      aosp[(size_t)row * 1024 + 512 + chb + ch] = lo;
    }
  }
}

// ---------------------------------------------------------------------------
extern "C" void kernel_launch(void* const* d_in, const int* in_sizes, int n_in,
                              void* d_out, int out_size, void* d_ws,
                              size_t ws_size, hipStream_t stream) {
  const float* value = (const float*)d_in[2];
  const float* noise = (const float*)d_in[4];
  const float* w_qkv = (const float*)d_in[5];
  const float* b_qkv = (const float*)d_in[6];
  const float* w_proj = (const float*)d_in[7];
  const float* b_proj = (const float*)d_in[8];
  const float* head_scores = (const float*)d_in[9];
  float* out = (float*)d_out;

  char* ws = (char*)d_ws;
  size_t o = 0;
  float* qkv = (float*)(ws + o);                 o += (size_t)NROWS * 1536 * 4;
  __hip_bfloat16* Qsp = (__hip_bfloat16*)(ws + o); o += (size_t)NROWS * 1024 * 2;
  __hip_bfloat16* Ksp = (__hip_bfloat16*)(ws + o); o += (size_t)NROWS * 1024 * 2;
  __hip_bfloat16* wpsp = (__hip_bfloat16*)(ws + o); o += (size_t)512 * 1024 * 2;
  float* thr = (float*)(ws + o);                 o += (size_t)NROWS * 4;
  unsigned long long* mask = (unsigned long long*)(ws + o); o += (size_t)NROWS * 32 * 8;
  __hip_bfloat16* aosp = (__hip_bfloat16*)(ws + o); o += (size_t)NROWS * 1024 * 2;
  float* z = (float*)(ws + o);                   o += (size_t)NROWS * NN * 4;
  float* Zpart = (float*)(ws + o);               o += (size_t)2 * NROWS * NH * 4;
  // valsp/wqsp alias z (dead before K2 writes z)
  __hip_bfloat16* valsp = (__hip_bfloat16*)z;
  __hip_bfloat16* wqsp = (__hip_bfloat16*)((char*)z + 8388608);
  // Khm aliases aosp (Khm read by denom_kernel; aosp written later by gather)
  __hip_bfloat16* Khm = aosp;

  // K0: split value / w_qkv / w_proj into (hi|lo) bf16 rows
  split_kernel<<<3072, 256, 0, stream>>>(value, w_qkv, w_proj, valsp, wqsp,
                                         wpsp);
  // K1: qkv = value @ w_qkv.T + b_qkv  (f32 qkv + Q,K splits + head-major K)
  gemm_bf16s<1><<<dim3(12, 32), 256, 0, stream>>>(
      valsp, 1024, wqsp, 1024, b_qkv, nullptr, nullptr, nullptr, 0, qkv, Qsp,
      Ksp, Khm);
  // K2: z = (scale/16) * Q @ K^T + gumbel(noise)
  gemm_bf16s<2><<<dim3(16, 32), 256, 0, stream>>>(
      Qsp, 1024, Ksp, 1024, nullptr, noise, nullptr, z, NN, nullptr, nullptr,
      nullptr, nullptr);
  // K3: per-row top-16 threshold + mask bits
  topk_kernel<<<NROWS, 256, 0, stream>>>(z, mask, thr);
  // K4a: per-head softmax denominators (head-major K, kv split x2)
  denom_kernel<<<dim3(64, 16, 2), 256, 0, stream>>>(Qsp, Khm, Zpart);
  // K4b: parallel sparse gather -> attn_out hi/lo split
  gather_kernel<<<dim3(NROWS / 8, NH), 256, 0, stream>>>(qkv, Zpart, mask,
                                                         aosp);
  // K5: out = (attn_out * mean(head_scores)) @ w_proj.T + b_proj
  gemm_bf16s<3><<<dim3(4, 32), 256, 0, stream>>>(
      aosp, 1024, wpsp, 1024, b_proj, nullptr, head_scores, out, NC, nullptr,
      nullptr, nullptr, nullptr);
}

// Round 7
// 324.035 us; speedup vs baseline: 1.6933x; 1.1181x over previous
//
#include <hip/hip_runtime.h>
#include <hip/hip_bf16.h>

// Problem constants (B=2, N=2048, C=512, H=16, dh=32, topk=16)
#define NB 2
#define NN 2048
#define NC 512
#define NH 16
#define NDH 32
#define NROWS (NB * NN) // 4096
#define KTOP 16

#define SCALE 0.17677669529663687f    // 1/sqrt(32)
#define SCALE16 0.011048543456039804f // SCALE/16

typedef __attribute__((ext_vector_type(8))) short bf16x8;
typedef __attribute__((ext_vector_type(4))) float f32x4;

// async global->LDS, 16B per lane (dest must be linear: base + lane*16)
#define GLD16(g, l)                                                      \
  __builtin_amdgcn_global_load_lds(                                      \
      (const __attribute__((address_space(1))) void*)(g),                \
      (__attribute__((address_space(3))) void*)(l), 16, 0, 0)

// ---------------------------------------------------------------------------
// Split fp32 -> (hi|lo) bf16 rows: out[row][0..511]=hi, out[row][512..1023]=lo
// ---------------------------------------------------------------------------
__global__ __launch_bounds__(256) void split_kernel(
    const float* __restrict__ val, const float* __restrict__ wq,
    const float* __restrict__ wp, __hip_bfloat16* __restrict__ valsp,
    __hip_bfloat16* __restrict__ wqsp, __hip_bfloat16* __restrict__ wpsp) {
  const int row = blockIdx.x * 2 + (threadIdx.x >> 7);
  const int kc = (threadIdx.x & 127) * 4;
  const float* src;
  __hip_bfloat16* dst;
  int rr;
  if (row < 4096) {
    src = val; dst = valsp; rr = row;
  } else if (row < 5632) {
    src = wq; dst = wqsp; rr = row - 4096;
  } else {
    src = wp; dst = wpsp; rr = row - 5632;
  }
  float4 x = *(const float4*)&src[(size_t)rr * 512 + kc];
  float xs[4] = {x.x, x.y, x.z, x.w};
#pragma unroll
  for (int j = 0; j < 4; j++) {
    __hip_bfloat16 hi = __float2bfloat16(xs[j]);
    __hip_bfloat16 lo = __float2bfloat16(xs[j] - __bfloat162float(hi));
    dst[(size_t)rr * 1024 + kc + j] = hi;
    dst[(size_t)rr * 1024 + 512 + kc + j] = lo;
  }
}

// ---------------------------------------------------------------------------
// Split-bf16 MFMA GEMM (3 passes: hi*hi + hi*lo + lo*hi), 128x128 tile, BK=64.
// EPI 1: +bias -> qkv f32; Q,K hi/lo splits; head-major K-hi copy (Khm).
// EPI 2: *SCALE16 + gumbel(noise) -> z
// EPI 3: *mean(head_scores) + bias -> out
// ---------------------------------------------------------------------------
template <int EPI>
__global__ __launch_bounds__(256, 2) void gemm_bf16s(
    const __hip_bfloat16* __restrict__ Aspg, int lda,
    const __hip_bfloat16* __restrict__ Bspg, int ldb,
    const float* __restrict__ bias, const float* __restrict__ noise,
    const float* __restrict__ hsp, float* __restrict__ Cc, int ldc,
    float* __restrict__ qkvf, __hip_bfloat16* __restrict__ Qsp,
    __hip_bfloat16* __restrict__ Ksp, __hip_bfloat16* __restrict__ Khm) {
  __shared__ short As[128 * 64];
  __shared__ short Bs[128 * 64];
  const int t = threadIdx.x;
  const int lane = t & 63;
  const int wv = t >> 6;
  const int wr = wv >> 1, wc = wv & 1;  // 2x2 wave grid, 64x64 per wave
  const int bm = blockIdx.y * 128;
  const int bn = blockIdx.x * 128;
  const short* Asp = (const short*)Aspg;
  const short* Bsp = (const short*)Bspg;
  if constexpr (EPI == 2) Bsp += (size_t)(bm >> 11) * 2048 * (size_t)ldb;

  const int r = lane & 15, g = lane >> 4;
  const int srow = t >> 3;       // staging row within 32-row group
  const int scol = (t & 7) * 8;  // staging col (elements)

  f32x4 acc[4][4];
#pragma unroll
  for (int m = 0; m < 4; m++)
#pragma unroll
    for (int n = 0; n < 4; n++) acc[m][n] = {0.f, 0.f, 0.f, 0.f};

  for (int s = 0; s < 24; s++) {
    const int pass = s >> 3;
    const int k0 = (s & 7) * 64;
    const int aoff = (pass == 2) ? 512 : 0;
    const int boff = (pass == 1) ? 512 : 0;
    __syncthreads();  // previous compute done before LDS overwrite
#pragma unroll
    for (int i = 0; i < 4; i++) {
      GLD16(Asp + (size_t)(bm + i * 32 + srow) * lda + aoff + k0 + scol,
            &As[i * 2048 + t * 8]);
      GLD16(Bsp + (size_t)(bn + i * 32 + srow) * ldb + boff + k0 + scol,
            &Bs[i * 2048 + t * 8]);
    }
    __syncthreads();  // staging drained
    bf16x8 af[4][2], bfr[4][2];
#pragma unroll
    for (int m = 0; m < 4; m++)
#pragma unroll
      for (int ks = 0; ks < 2; ks++)
        af[m][ks] =
            *(const bf16x8*)&As[(wr * 64 + m * 16 + r) * 64 + ks * 32 + g * 8];
#pragma unroll
    for (int n = 0; n < 4; n++)
#pragma unroll
      for (int ks = 0; ks < 2; ks++)
        bfr[n][ks] =
            *(const bf16x8*)&Bs[(wc * 64 + n * 16 + r) * 64 + ks * 32 + g * 8];
#pragma unroll
    for (int m = 0; m < 4; m++)
#pragma unroll
      for (int n = 0; n < 4; n++) {
        acc[m][n] = __builtin_amdgcn_mfma_f32_16x16x32_bf16(
            af[m][0], bfr[n][0], acc[m][n], 0, 0, 0);
        acc[m][n] = __builtin_amdgcn_mfma_f32_16x16x32_bf16(
            af[m][1], bfr[n][1], acc[m][n], 0, 0, 0);
      }
  }

  float hs = 1.0f;
  if constexpr (EPI == 3) {
    float ssum = 0.f;
#pragma unroll
    for (int i = 0; i < NH; i++) ssum += hsp[i];
    hs = ssum * (1.0f / NH);
  }

  // C/D layout (m89-verified): col = lane&15, row = (lane>>4)*4 + reg
#pragma unroll
  for (int m = 0; m < 4; m++)
#pragma unroll
    for (int n = 0; n < 4; n++)
#pragma unroll
      for (int j = 0; j < 4; j++) {
        const int row = bm + wr * 64 + m * 16 + g * 4 + j;
        const int col = bn + wc * 64 + n * 16 + r;
        float x = acc[m][n][j];
        if constexpr (EPI == 1) {
          x += bias[col];
          qkvf[(size_t)row * 1536 + col] = x;
          if (col < 1024) {  // Q,K: hi/lo split for K2
            __hip_bfloat16 hi = __float2bfloat16(x);
            __hip_bfloat16 lo = __float2bfloat16(x - __bfloat162float(hi));
            __hip_bfloat16* dst = (col < 512) ? Qsp : Ksp;
            const int c = col & 511;
            dst[(size_t)row * 1024 + c] = hi;
            dst[(size_t)row * 1024 + c + 512] = lo;
            if (col >= 512) {  // head-major K-hi for denom kernel
              const int kc = col - 512;
              Khm[((size_t)(kc >> 5) * NROWS + row) * NDH + (kc & 31)] = hi;
            }
          }
        } else if constexpr (EPI == 2) {
          const int bb = row >> 11;
          const int nr = row & (NN - 1);
          float u = noise[((size_t)bb << 22) + ((size_t)nr << 11) + col];
          float gum = -logf(-logf(u + 1e-9f) + 1e-9f);
          Cc[(size_t)row * ldc + col] = x * SCALE16 + gum;
        } else {
          Cc[(size_t)row * ldc + col] = x * hs + bias[col];
        }
      }
}

// ---------------------------------------------------------------------------
// K3: per-row top-16, one WAVE per row, no LDS, no barriers.
// Lane l holds elements {r*64+l, r=0..31} in registers (static indices only).
// Iterated argmax: 6-shuffle max over cached lane-local maxes; winner lane
// removes one instance and recomputes its local max (divergent, 1 lane).
// Mask: ballot over reg r == mask word r exactly.
// ---------------------------------------------------------------------------
__global__ __launch_bounds__(256) void topk_kernel(
    const float* __restrict__ z, unsigned long long* __restrict__ mask) {
  const int lane = threadIdx.x & 63;
  const int row = blockIdx.x * 4 + (threadIdx.x >> 6);
  const float* zr = z + (size_t)row * NN;

  float v[32];
#pragma unroll
  for (int r = 0; r < 32; r++) v[r] = zr[r * 64 + lane];

  float lmax = v[0];
#pragma unroll
  for (int r = 1; r < 32; r++) lmax = fmaxf(lmax, v[r]);

  float thresh = 0.f;
  for (int it = 0; it < KTOP; it++) {
    float m = lmax;
#pragma unroll
    for (int s = 1; s < 64; s <<= 1) m = fmaxf(m, __shfl_xor(m, s));
    thresh = m;
    const unsigned long long ball = __ballot(lmax == m);
    if (lane == (int)__builtin_ctzll(ball)) {
      // remove exactly one instance equal to m, then recompute local max
      bool done = false;
#pragma unroll
      for (int r = 0; r < 32; r++) {
        const bool hit = !done && (v[r] == m);
        if (hit) v[r] = -INFINITY;
        done = done || hit;
      }
      lmax = v[0];
#pragma unroll
      for (int r = 1; r < 32; r++) lmax = fmaxf(lmax, v[r]);
    }
  }

  // mask word r = ballot(z[r*64+lane] >= thresh); reload pristine z (L2-hot)
  unsigned long long mword = 0ull;
#pragma unroll
  for (int r = 0; r < 32; r++) {
    const unsigned long long bal = __ballot(zr[r * 64 + lane] >= thresh);
    if (lane == r) mword = bal;
  }
  if (lane < 32) mask[(size_t)row * 32 + lane] = mword;
}

// ---------------------------------------------------------------------------
// K4a: per-head softmax denominators via MFMA over head-major K-hi.
// Grid (64 rowgroups, 16 heads, 2 kv-chunks); wave = 16 Q-rows; no LDS.
// Writes Zpart[chunk][row][head] (two-part deterministic sum).
// ---------------------------------------------------------------------------
__global__ __launch_bounds__(256) void denom_kernel(
    const __hip_bfloat16* __restrict__ Qsp, const __hip_bfloat16* __restrict__ Khm,
    float* __restrict__ Zpart) {
  const int lane = threadIdx.x & 63;
  const int wave = threadIdx.x >> 6;
  const int rowbase = blockIdx.x * 64 + wave * 16;
  const int h = blockIdx.y;
  const int chunk = blockIdx.z;
  const int b = rowbase >> 11;
  const int rl = lane & 15;
  const int g = lane >> 4;

  const short* qb = (const short*)Qsp;
  bf16x8 afrag =
      *(const bf16x8*)&qb[(size_t)(rowbase + rl) * 1024 + h * NDH + g * 8];
  const short* kb = (const short*)Khm +
                    ((size_t)h * NROWS + (b << 11) + chunk * 1024) * NDH;
  float sum[4] = {0.f, 0.f, 0.f, 0.f};
  for (int m0 = 0; m0 < 1024; m0 += 32) {
    bf16x8 b0 = *(const bf16x8*)&kb[(m0 + rl) * NDH + g * 8];
    bf16x8 b1 = *(const bf16x8*)&kb[(m0 + 16 + rl) * NDH + g * 8];
    f32x4 zero = {0.f, 0.f, 0.f, 0.f};
    f32x4 d0 =
        __builtin_amdgcn_mfma_f32_16x16x32_bf16(afrag, b0, zero, 0, 0, 0);
    f32x4 d1 =
        __builtin_amdgcn_mfma_f32_16x16x32_bf16(afrag, b1, zero, 0, 0, 0);
#pragma unroll
    for (int j = 0; j < 4; j++)
      sum[j] += __expf(d0[j] * SCALE) + __expf(d1[j] * SCALE);
  }
#pragma unroll
  for (int j = 0; j < 4; j++)
#pragma unroll
    for (int s = 1; s < 16; s <<= 1) sum[j] += __shfl_xor(sum[j], s);
  if (rl == 0) {
#pragma unroll
    for (int j = 0; j < 4; j++) {
      const int row = rowbase + g * 4 + j;
      Zpart[((size_t)chunk << 16) + (size_t)row * NH + h] = sum[j];
    }
  }
}

// ---------------------------------------------------------------------------
// K4b: sparse gather, all hits in parallel. Wave = 2 rows x 1 head; per row
// 32 lanes: collect hit indices (ballot prefix-scan -> LDS), then 2 lanes/hit
// x 16 ch process up to 16 hits concurrently. Writes hi/lo split attn_out.
// ---------------------------------------------------------------------------
__global__ __launch_bounds__(256) void gather_kernel(
    const float* __restrict__ qkv, const float* __restrict__ Zpart,
    const unsigned long long* __restrict__ mask,
    __hip_bfloat16* __restrict__ aosp) {
  const int t = threadIdx.x;
  const int lane = t & 63;
  const int wave = t >> 6;
  const int l32 = lane & 31;
  const int rhalf = lane >> 5;
  const int row = blockIdx.x * 8 + wave * 2 + rhalf;
  const int h = blockIdx.y;
  const int b = row >> 11;
  const int rloc = wave * 2 + rhalf;

  __shared__ int idxbuf[8][64];
  __shared__ int cnts[8];

  // ---- collect hit indices: lane l32 scans mask word l32 ----
  const unsigned long long* mrow = mask + (size_t)row * 32;
  unsigned long long bits = mrow[l32];
  int c = __popcll(bits);
  int p = c;
#pragma unroll
  for (int d = 1; d < 32; d <<= 1) {
    int o = __shfl_up(p, d, 32);
    if (l32 >= d) p += o;
  }
  int total = __shfl(p, 31, 32);
  p -= c;  // exclusive prefix
  while (bits) {
    int tz = __builtin_ctzll(bits);
    bits &= bits - 1;
    if (p < 64) idxbuf[rloc][p] = (l32 << 6) + tz;
    p++;
  }
  if (l32 == 0) cnts[rloc] = total > 64 ? 64 : total;
  __syncthreads();
  const int cnt = cnts[rloc];

  // ---- parallel gather: 2 lanes per hit, 16 channels per lane ----
  const int chb = h * NDH + (l32 & 1) * 16;
  const float* qrow = qkv + (size_t)row * 1536 + chb;
  float q0[16];
#pragma unroll
  for (int i = 0; i < 4; i++)
    *(float4*)&q0[i * 4] = *(const float4*)&qrow[i * 4];
  const float* Kf = qkv + (size_t)(b << 11) * 1536 + 512 + chb;
  const float* Vf = qkv + (size_t)(b << 11) * 1536 + 1024 + chb;
  float acc[16] = {};
  for (int base = 0; base < cnt; base += 16) {
    const int hit = base + (l32 >> 1);
    const bool valid = hit < cnt;
    const int m = valid ? idxbuf[rloc][hit] : 0;
    const float* kr = Kf + (size_t)m * 1536;
    float part = 0.f;
#pragma unroll
    for (int i = 0; i < 4; i++) {
      float4 kv4 = *(const float4*)&kr[i * 4];
      part = fmaf(q0[i * 4 + 0], kv4.x, part);
      part = fmaf(q0[i * 4 + 1], kv4.y, part);
      part = fmaf(q0[i * 4 + 2], kv4.z, part);
      part = fmaf(q0[i * 4 + 3], kv4.w, part);
    }
    part += __shfl_xor(part, 1);  // combine the channel-halves of this hit
    const float pexp = valid ? __expf(part * SCALE) : 0.f;
    const float* vr = Vf + (size_t)m * 1536;
#pragma unroll
    for (int i = 0; i < 4; i++) {
      float4 vv4 = *(const float4*)&vr[i * 4];
      acc[i * 4 + 0] = fmaf(pexp, vv4.x, acc[i * 4 + 0]);
      acc[i * 4 + 1] = fmaf(pexp, vv4.y, acc[i * 4 + 1]);
      acc[i * 4 + 2] = fmaf(pexp, vv4.z, acc[i * 4 + 2]);
      acc[i * 4 + 3] = fmaf(pexp, vv4.w, acc[i * 4 + 3]);
    }
  }
  // sum across the 16 hit-pairs (keeps channel-half split on bit 0)
#pragma unroll
  for (int s = 2; s < 32; s <<= 1)
#pragma unroll
    for (int ch = 0; ch < 16; ch++) acc[ch] += __shfl_xor(acc[ch], s);

  if (l32 < 2) {
    const float Z = Zpart[(size_t)row * NH + h] +
                    Zpart[(1 << 16) + (size_t)row * NH + h];
    const float Zinv = 1.0f / Z;
#pragma unroll
    for (int ch = 0; ch < 16; ch++) {
      const float v = acc[ch] * Zinv;
      __hip_bfloat16 hi = __float2bfloat16(v);
      __hip_bfloat16 lo = __float2bfloat16(v - __bfloat162float(hi));
      aosp[(size_t)row * 1024 + chb + ch] = hi;
      aosp[(size_t)row * 1024 + 512 + chb + ch] = lo;
    }
  }
}

// ---------------------------------------------------------------------------
extern "C" void kernel_launch(void* const* d_in, const int* in_sizes, int n_in,
                              void* d_out, int out_size, void* d_ws,
                              size_t ws_size, hipStream_t stream) {
  const float* value = (const float*)d_in[2];
  const float* noise = (const float*)d_in[4];
  const float* w_qkv = (const float*)d_in[5];
  const float* b_qkv = (const float*)d_in[6];
  const float* w_proj = (const float*)d_in[7];
  const float* b_proj = (const float*)d_in[8];
  const float* head_scores = (const float*)d_in[9];
  float* out = (float*)d_out;

  char* ws = (char*)d_ws;
  size_t o = 0;
  float* qkv = (float*)(ws + o);                 o += (size_t)NROWS * 1536 * 4;
  __hip_bfloat16* Qsp = (__hip_bfloat16*)(ws + o); o += (size_t)NROWS * 1024 * 2;
  __hip_bfloat16* Ksp = (__hip_bfloat16*)(ws + o); o += (size_t)NROWS * 1024 * 2;
  __hip_bfloat16* wpsp = (__hip_bfloat16*)(ws + o); o += (size_t)512 * 1024 * 2;
  unsigned long long* mask = (unsigned long long*)(ws + o); o += (size_t)NROWS * 32 * 8;
  __hip_bfloat16* aosp = (__hip_bfloat16*)(ws + o); o += (size_t)NROWS * 1024 * 2;
  float* z = (float*)(ws + o);                   o += (size_t)NROWS * NN * 4;
  float* Zpart = (float*)(ws + o);               o += (size_t)2 * NROWS * NH * 4;
  // valsp/wqsp alias z (dead before K2 writes z)
  __hip_bfloat16* valsp = (__hip_bfloat16*)z;
  __hip_bfloat16* wqsp = (__hip_bfloat16*)((char*)z + 8388608);
  // Khm aliases aosp (Khm read by denom_kernel; aosp written later by gather)
  __hip_bfloat16* Khm = aosp;

  // K0: split value / w_qkv / w_proj into (hi|lo) bf16 rows
  split_kernel<<<3072, 256, 0, stream>>>(value, w_qkv, w_proj, valsp, wqsp,
                                         wpsp);
  // K1: qkv = value @ w_qkv.T + b_qkv  (f32 qkv + Q,K splits + head-major K)
  gemm_bf16s<1><<<dim3(12, 32), 256, 0, stream>>>(
      valsp, 1024, wqsp, 1024, b_qkv, nullptr, nullptr, nullptr, 0, qkv, Qsp,
      Ksp, Khm);
  // K2: z = (scale/16) * Q @ K^T + gumbel(noise)
  gemm_bf16s<2><<<dim3(16, 32), 256, 0, stream>>>(
      Qsp, 1024, Ksp, 1024, nullptr, noise, nullptr, z, NN, nullptr, nullptr,
      nullptr, nullptr);
  // K3: per-row top-16 threshold + mask bits (one wave per row)
  topk_kernel<<<NROWS / 4, 256, 0, stream>>>(z, mask);
  // K4a: per-head softmax denominators (head-major K, kv split x2)
  denom_kernel<<<dim3(64, 16, 2), 256, 0, stream>>>(Qsp, Khm, Zpart);
  // K4b: parallel sparse gather -> attn_out hi/lo split
  gather_kernel<<<dim3(NROWS / 8, NH), 256, 0, stream>>>(qkv, Zpart, mask,
                                                         aosp);
  // K5: out = (attn_out * mean(head_scores)) @ w_proj.T + b_proj
  gemm_bf16s<3><<<dim3(4, 32), 256, 0, stream>>>(
      aosp, 1024, wpsp, 1024, b_proj, nullptr, head_scores, out, NC, nullptr,
      nullptr, nullptr, nullptr);
}

// Round 8
// 283.959 us; speedup vs baseline: 1.9323x; 1.1411x over previous
//
#include <hip/hip_runtime.h>
#include <hip/hip_bf16.h>

// Problem constants (B=2, N=2048, C=512, H=16, dh=32, topk=16)
#define NB 2
#define NN 2048
#define NC 512
#define NH 16
#define NDH 32
#define NROWS (NB * NN) // 4096
#define KTOP 16

#define SCALE 0.17677669529663687f    // 1/sqrt(32)
#define SCALE16 0.011048543456039804f // SCALE/16

typedef __attribute__((ext_vector_type(8))) short bf16x8;
typedef __attribute__((ext_vector_type(4))) float f32x4;

// async global->LDS, 16B per lane (dest must be linear: base + lane*16)
#define GLD16(g, l)                                                      \
  __builtin_amdgcn_global_load_lds(                                      \
      (const __attribute__((address_space(1))) void*)(g),                \
      (__attribute__((address_space(3))) void*)(l), 16, 0, 0)

// ---------------------------------------------------------------------------
// Split fp32 -> (hi|lo) bf16 rows: out[row][0..511]=hi, out[row][512..1023]=lo
// ---------------------------------------------------------------------------
__global__ __launch_bounds__(256) void split_kernel(
    const float* __restrict__ val, const float* __restrict__ wq,
    const float* __restrict__ wp, __hip_bfloat16* __restrict__ valsp,
    __hip_bfloat16* __restrict__ wqsp, __hip_bfloat16* __restrict__ wpsp) {
  const int row = blockIdx.x * 2 + (threadIdx.x >> 7);
  const int kc = (threadIdx.x & 127) * 4;
  const float* src;
  __hip_bfloat16* dst;
  int rr;
  if (row < 4096) {
    src = val; dst = valsp; rr = row;
  } else if (row < 5632) {
    src = wq; dst = wqsp; rr = row - 4096;
  } else {
    src = wp; dst = wpsp; rr = row - 5632;
  }
  float4 x = *(const float4*)&src[(size_t)rr * 512 + kc];
  float xs[4] = {x.x, x.y, x.z, x.w};
#pragma unroll
  for (int j = 0; j < 4; j++) {
    __hip_bfloat16 hi = __float2bfloat16(xs[j]);
    __hip_bfloat16 lo = __float2bfloat16(xs[j] - __bfloat162float(hi));
    dst[(size_t)rr * 1024 + kc + j] = hi;
    dst[(size_t)rr * 1024 + 512 + kc + j] = lo;
  }
}

// ---------------------------------------------------------------------------
// Split-bf16 MFMA GEMM, single K-sweep: per BK=64 step stage Ahi/Alo/Bhi/Blo
// (64 KB LDS) and run 3 combos (hi*lo, hi*hi, lo*hi) re-reading only the
// changed operand. LDS XOR-swizzle (granule ^= row&7) applied via
// pre-swizzled GLOBAL source (global_load_lds dest must stay linear) and
// swizzled ds_read addresses — bank-conflict-free fragment reads.
// EPI 1: +bias -> qkv f32; Q,K hi/lo splits; head-major K-hi copy (Khm).
// EPI 2: *SCALE16 + gumbel(noise) -> z
// EPI 3: *mean(head_scores) + bias -> out
// ---------------------------------------------------------------------------
template <int EPI>
__global__ __launch_bounds__(256, 2) void gemm_bf16s(
    const __hip_bfloat16* __restrict__ Aspg, int lda,
    const __hip_bfloat16* __restrict__ Bspg, int ldb,
    const float* __restrict__ bias, const float* __restrict__ noise,
    const float* __restrict__ hsp, float* __restrict__ Cc, int ldc,
    float* __restrict__ qkvf, __hip_bfloat16* __restrict__ Qsp,
    __hip_bfloat16* __restrict__ Ksp, __hip_bfloat16* __restrict__ Khm) {
  __shared__ short Ah[128 * 64];
  __shared__ short Al[128 * 64];
  __shared__ short Bh[128 * 64];
  __shared__ short Bl[128 * 64];
  const int t = threadIdx.x;
  const int lane = t & 63;
  const int wv = t >> 6;
  const int wr = wv >> 1, wc = wv & 1;  // 2x2 wave grid, 64x64 per wave
  const int bm = blockIdx.y * 128;
  const int bn = blockIdx.x * 128;
  const short* Asp = (const short*)Aspg;
  const short* Bsp = (const short*)Bspg;
  if constexpr (EPI == 2) Bsp += (size_t)(bm >> 11) * 2048 * (size_t)ldb;

  const int r = lane & 15, g = lane >> 4;
  const int srow = t >> 3;  // staging row within 32-row group
  // pre-swizzled source granule: LDS[row][gi] <- global[row][gi ^ (row&7)]
  const int scol = (((t & 7) ^ ((t >> 3) & 7)) * 8);

  f32x4 acc[4][4];
#pragma unroll
  for (int m = 0; m < 4; m++)
#pragma unroll
    for (int n = 0; n < 4; n++) acc[m][n] = {0.f, 0.f, 0.f, 0.f};

  // swizzled fragment read: row*64 + ((ks*4+g) ^ (r&7))*8 shorts
  const int rx = r & 7;

  for (int s = 0; s < 8; s++) {
    const int k0 = s * 64;
    __syncthreads();  // previous compute done before LDS overwrite
#pragma unroll
    for (int i = 0; i < 4; i++) {
      const size_t ar = (size_t)(bm + i * 32 + srow) * lda + k0 + scol;
      const size_t br = (size_t)(bn + i * 32 + srow) * ldb + k0 + scol;
      GLD16(Asp + ar, &Ah[i * 2048 + t * 8]);
      GLD16(Asp + ar + 512, &Al[i * 2048 + t * 8]);
      GLD16(Bsp + br, &Bh[i * 2048 + t * 8]);
      GLD16(Bsp + br + 512, &Bl[i * 2048 + t * 8]);
    }
    __syncthreads();  // staging drained (compiler emits vmcnt(0) before barrier)

    bf16x8 af[4][2], bfr[4][2];
    // combo 1: A-hi x B-lo
#pragma unroll
    for (int m = 0; m < 4; m++)
#pragma unroll
      for (int ks = 0; ks < 2; ks++)
        af[m][ks] = *(const bf16x8*)&Ah[(wr * 64 + m * 16 + r) * 64 +
                                        ((ks * 4 + g) ^ rx) * 8];
#pragma unroll
    for (int n = 0; n < 4; n++)
#pragma unroll
      for (int ks = 0; ks < 2; ks++)
        bfr[n][ks] = *(const bf16x8*)&Bl[(wc * 64 + n * 16 + r) * 64 +
                                         ((ks * 4 + g) ^ rx) * 8];
#pragma unroll
    for (int m = 0; m < 4; m++)
#pragma unroll
      for (int n = 0; n < 4; n++) {
        acc[m][n] = __builtin_amdgcn_mfma_f32_16x16x32_bf16(
            af[m][0], bfr[n][0], acc[m][n], 0, 0, 0);
        acc[m][n] = __builtin_amdgcn_mfma_f32_16x16x32_bf16(
            af[m][1], bfr[n][1], acc[m][n], 0, 0, 0);
      }
    // combo 2: A-hi x B-hi (reload B only)
#pragma unroll
    for (int n = 0; n < 4; n++)
#pragma unroll
      for (int ks = 0; ks < 2; ks++)
        bfr[n][ks] = *(const bf16x8*)&Bh[(wc * 64 + n * 16 + r) * 64 +
                                         ((ks * 4 + g) ^ rx) * 8];
#pragma unroll
    for (int m = 0; m < 4; m++)
#pragma unroll
      for (int n = 0; n < 4; n++) {
        acc[m][n] = __builtin_amdgcn_mfma_f32_16x16x32_bf16(
            af[m][0], bfr[n][0], acc[m][n], 0, 0, 0);
        acc[m][n] = __builtin_amdgcn_mfma_f32_16x16x32_bf16(
            af[m][1], bfr[n][1], acc[m][n], 0, 0, 0);
      }
    // combo 3: A-lo x B-hi (reload A only)
#pragma unroll
    for (int m = 0; m < 4; m++)
#pragma unroll
      for (int ks = 0; ks < 2; ks++)
        af[m][ks] = *(const bf16x8*)&Al[(wr * 64 + m * 16 + r) * 64 +
                                        ((ks * 4 + g) ^ rx) * 8];
#pragma unroll
    for (int m = 0; m < 4; m++)
#pragma unroll
      for (int n = 0; n < 4; n++) {
        acc[m][n] = __builtin_amdgcn_mfma_f32_16x16x32_bf16(
            af[m][0], bfr[n][0], acc[m][n], 0, 0, 0);
        acc[m][n] = __builtin_amdgcn_mfma_f32_16x16x32_bf16(
            af[m][1], bfr[n][1], acc[m][n], 0, 0, 0);
      }
  }

  float hs = 1.0f;
  if constexpr (EPI == 3) {
    float ssum = 0.f;
#pragma unroll
    for (int i = 0; i < NH; i++) ssum += hsp[i];
    hs = ssum * (1.0f / NH);
  }

  // C/D layout (m89-verified): col = lane&15, row = (lane>>4)*4 + reg
#pragma unroll
  for (int m = 0; m < 4; m++)
#pragma unroll
    for (int n = 0; n < 4; n++)
#pragma unroll
      for (int j = 0; j < 4; j++) {
        const int row = bm + wr * 64 + m * 16 + g * 4 + j;
        const int col = bn + wc * 64 + n * 16 + r;
        float x = acc[m][n][j];
        if constexpr (EPI == 1) {
          x += bias[col];
          qkvf[(size_t)row * 1536 + col] = x;
          if (col < 1024) {  // Q,K: hi/lo split for K2
            __hip_bfloat16 hi = __float2bfloat16(x);
            __hip_bfloat16 lo = __float2bfloat16(x - __bfloat162float(hi));
            __hip_bfloat16* dst = (col < 512) ? Qsp : Ksp;
            const int c = col & 511;
            dst[(size_t)row * 1024 + c] = hi;
            dst[(size_t)row * 1024 + c + 512] = lo;
            if (col >= 512) {  // head-major K-hi for denom kernel
              const int kc = col - 512;
              Khm[((size_t)(kc >> 5) * NROWS + row) * NDH + (kc & 31)] = hi;
            }
          }
        } else if constexpr (EPI == 2) {
          const int bb = row >> 11;
          const int nr = row & (NN - 1);
          float u = noise[((size_t)bb << 22) + ((size_t)nr << 11) + col];
          float gum = -logf(-logf(u + 1e-9f) + 1e-9f);
          Cc[(size_t)row * ldc + col] = x * SCALE16 + gum;
        } else {
          Cc[(size_t)row * ldc + col] = x * hs + bias[col];
        }
      }
}

// ---------------------------------------------------------------------------
// K3: per-row top-16, one WAVE per row, no LDS, no barriers.
// ---------------------------------------------------------------------------
__global__ __launch_bounds__(256) void topk_kernel(
    const float* __restrict__ z, unsigned long long* __restrict__ mask) {
  const int lane = threadIdx.x & 63;
  const int row = blockIdx.x * 4 + (threadIdx.x >> 6);
  const float* zr = z + (size_t)row * NN;

  float v[32];
#pragma unroll
  for (int r = 0; r < 32; r++) v[r] = zr[r * 64 + lane];

  float lmax = v[0];
#pragma unroll
  for (int r = 1; r < 32; r++) lmax = fmaxf(lmax, v[r]);

  float thresh = 0.f;
  for (int it = 0; it < KTOP; it++) {
    float m = lmax;
#pragma unroll
    for (int s = 1; s < 64; s <<= 1) m = fmaxf(m, __shfl_xor(m, s));
    thresh = m;
    const unsigned long long ball = __ballot(lmax == m);
    if (lane == (int)__builtin_ctzll(ball)) {
      bool done = false;
#pragma unroll
      for (int r = 0; r < 32; r++) {
        const bool hit = !done && (v[r] == m);
        if (hit) v[r] = -INFINITY;
        done = done || hit;
      }
      lmax = v[0];
#pragma unroll
      for (int r = 1; r < 32; r++) lmax = fmaxf(lmax, v[r]);
    }
  }

  unsigned long long mword = 0ull;
#pragma unroll
  for (int r = 0; r < 32; r++) {
    const unsigned long long bal = __ballot(zr[r * 64 + lane] >= thresh);
    if (lane == r) mword = bal;
  }
  if (lane < 32) mask[(size_t)row * 32 + lane] = mword;
}

// ---------------------------------------------------------------------------
// K4a: per-head softmax denominators via MFMA over head-major K-hi.
// ---------------------------------------------------------------------------
__global__ __launch_bounds__(256) void denom_kernel(
    const __hip_bfloat16* __restrict__ Qsp, const __hip_bfloat16* __restrict__ Khm,
    float* __restrict__ Zpart) {
  const int lane = threadIdx.x & 63;
  const int wave = threadIdx.x >> 6;
  const int rowbase = blockIdx.x * 64 + wave * 16;
  const int h = blockIdx.y;
  const int chunk = blockIdx.z;
  const int b = rowbase >> 11;
  const int rl = lane & 15;
  const int g = lane >> 4;

  const short* qb = (const short*)Qsp;
  bf16x8 afrag =
      *(const bf16x8*)&qb[(size_t)(rowbase + rl) * 1024 + h * NDH + g * 8];
  const short* kb = (const short*)Khm +
                    ((size_t)h * NROWS + (b << 11) + chunk * 1024) * NDH;
  float sum[4] = {0.f, 0.f, 0.f, 0.f};
  for (int m0 = 0; m0 < 1024; m0 += 32) {
    bf16x8 b0 = *(const bf16x8*)&kb[(m0 + rl) * NDH + g * 8];
    bf16x8 b1 = *(const bf16x8*)&kb[(m0 + 16 + rl) * NDH + g * 8];
    f32x4 zero = {0.f, 0.f, 0.f, 0.f};
    f32x4 d0 =
        __builtin_amdgcn_mfma_f32_16x16x32_bf16(afrag, b0, zero, 0, 0, 0);
    f32x4 d1 =
        __builtin_amdgcn_mfma_f32_16x16x32_bf16(afrag, b1, zero, 0, 0, 0);
#pragma unroll
    for (int j = 0; j < 4; j++)
      sum[j] += __expf(d0[j] * SCALE) + __expf(d1[j] * SCALE);
  }
#pragma unroll
  for (int j = 0; j < 4; j++)
#pragma unroll
    for (int s = 1; s < 16; s <<= 1) sum[j] += __shfl_xor(sum[j], s);
  if (rl == 0) {
#pragma unroll
    for (int j = 0; j < 4; j++) {
      const int row = rowbase + g * 4 + j;
      Zpart[((size_t)chunk << 16) + (size_t)row * NH + h] = sum[j];
    }
  }
}

// ---------------------------------------------------------------------------
// K4b: sparse gather, all hits in parallel. Wave = 2 rows x 1 head.
// ---------------------------------------------------------------------------
__global__ __launch_bounds__(256) void gather_kernel(
    const float* __restrict__ qkv, const float* __restrict__ Zpart,
    const unsigned long long* __restrict__ mask,
    __hip_bfloat16* __restrict__ aosp) {
  const int t = threadIdx.x;
  const int lane = t & 63;
  const int wave = t >> 6;
  const int l32 = lane & 31;
  const int rhalf = lane >> 5;
  const int row = blockIdx.x * 8 + wave * 2 + rhalf;
  const int h = blockIdx.y;
  const int b = row >> 11;
  const int rloc = wave * 2 + rhalf;

  __shared__ int idxbuf[8][64];
  __shared__ int cnts[8];

  const unsigned long long* mrow = mask + (size_t)row * 32;
  unsigned long long bits = mrow[l32];
  int c = __popcll(bits);
  int p = c;
#pragma unroll
  for (int d = 1; d < 32; d <<= 1) {
    int o = __shfl_up(p, d, 32);
    if (l32 >= d) p += o;
  }
  int total = __shfl(p, 31, 32);
  p -= c;  // exclusive prefix
  while (bits) {
    int tz = __builtin_ctzll(bits);
    bits &= bits - 1;
    if (p < 64) idxbuf[rloc][p] = (l32 << 6) + tz;
    p++;
  }
  if (l32 == 0) cnts[rloc] = total > 64 ? 64 : total;
  __syncthreads();
  const int cnt = cnts[rloc];

  const int chb = h * NDH + (l32 & 1) * 16;
  const float* qrow = qkv + (size_t)row * 1536 + chb;
  float q0[16];
#pragma unroll
  for (int i = 0; i < 4; i++)
    *(float4*)&q0[i * 4] = *(const float4*)&qrow[i * 4];
  const float* Kf = qkv + (size_t)(b << 11) * 1536 + 512 + chb;
  const float* Vf = qkv + (size_t)(b << 11) * 1536 + 1024 + chb;
  float acc[16] = {};
  for (int base = 0; base < cnt; base += 16) {
    const int hit = base + (l32 >> 1);
    const bool valid = hit < cnt;
    const int m = valid ? idxbuf[rloc][hit] : 0;
    const float* kr = Kf + (size_t)m * 1536;
    float part = 0.f;
#pragma unroll
    for (int i = 0; i < 4; i++) {
      float4 kv4 = *(const float4*)&kr[i * 4];
      part = fmaf(q0[i * 4 + 0], kv4.x, part);
      part = fmaf(q0[i * 4 + 1], kv4.y, part);
      part = fmaf(q0[i * 4 + 2], kv4.z, part);
      part = fmaf(q0[i * 4 + 3], kv4.w, part);
    }
    part += __shfl_xor(part, 1);
    const float pexp = valid ? __expf(part * SCALE) : 0.f;
    const float* vr = Vf + (size_t)m * 1536;
#pragma unroll
    for (int i = 0; i < 4; i++) {
      float4 vv4 = *(const float4*)&vr[i * 4];
      acc[i * 4 + 0] = fmaf(pexp, vv4.x, acc[i * 4 + 0]);
      acc[i * 4 + 1] = fmaf(pexp, vv4.y, acc[i * 4 + 1]);
      acc[i * 4 + 2] = fmaf(pexp, vv4.z, acc[i * 4 + 2]);
      acc[i * 4 + 3] = fmaf(pexp, vv4.w, acc[i * 4 + 3]);
    }
  }
#pragma unroll
  for (int s = 2; s < 32; s <<= 1)
#pragma unroll
    for (int ch = 0; ch < 16; ch++) acc[ch] += __shfl_xor(acc[ch], s);

  if (l32 < 2) {
    const float Z = Zpart[(size_t)row * NH + h] +
                    Zpart[(1 << 16) + (size_t)row * NH + h];
    const float Zinv = 1.0f / Z;
#pragma unroll
    for (int ch = 0; ch < 16; ch++) {
      const float v = acc[ch] * Zinv;
      __hip_bfloat16 hi = __float2bfloat16(v);
      __hip_bfloat16 lo = __float2bfloat16(v - __bfloat162float(hi));
      aosp[(size_t)row * 1024 + chb + ch] = hi;
      aosp[(size_t)row * 1024 + 512 + chb + ch] = lo;
    }
  }
}

// ---------------------------------------------------------------------------
extern "C" void kernel_launch(void* const* d_in, const int* in_sizes, int n_in,
                              void* d_out, int out_size, void* d_ws,
                              size_t ws_size, hipStream_t stream) {
  const float* value = (const float*)d_in[2];
  const float* noise = (const float*)d_in[4];
  const float* w_qkv = (const float*)d_in[5];
  const float* b_qkv = (const float*)d_in[6];
  const float* w_proj = (const float*)d_in[7];
  const float* b_proj = (const float*)d_in[8];
  const float* head_scores = (const float*)d_in[9];
  float* out = (float*)d_out;

  char* ws = (char*)d_ws;
  size_t o = 0;
  float* qkv = (float*)(ws + o);                 o += (size_t)NROWS * 1536 * 4;
  __hip_bfloat16* Qsp = (__hip_bfloat16*)(ws + o); o += (size_t)NROWS * 1024 * 2;
  __hip_bfloat16* Ksp = (__hip_bfloat16*)(ws + o); o += (size_t)NROWS * 1024 * 2;
  __hip_bfloat16* wpsp = (__hip_bfloat16*)(ws + o); o += (size_t)512 * 1024 * 2;
  unsigned long long* mask = (unsigned long long*)(ws + o); o += (size_t)NROWS * 32 * 8;
  __hip_bfloat16* aosp = (__hip_bfloat16*)(ws + o); o += (size_t)NROWS * 1024 * 2;
  float* z = (float*)(ws + o);                   o += (size_t)NROWS * NN * 4;
  float* Zpart = (float*)(ws + o);               o += (size_t)2 * NROWS * NH * 4;
  // valsp/wqsp alias z (dead before K2 writes z)
  __hip_bfloat16* valsp = (__hip_bfloat16*)z;
  __hip_bfloat16* wqsp = (__hip_bfloat16*)((char*)z + 8388608);
  // Khm aliases aosp (Khm read by denom_kernel; aosp written later by gather)
  __hip_bfloat16* Khm = aosp;

  // K0: split value / w_qkv / w_proj into (hi|lo) bf16 rows
  split_kernel<<<3072, 256, 0, stream>>>(value, w_qkv, w_proj, valsp, wqsp,
                                         wpsp);
  // K1: qkv = value @ w_qkv.T + b_qkv  (f32 qkv + Q,K splits + head-major K)
  gemm_bf16s<1><<<dim3(12, 32), 256, 0, stream>>>(
      valsp, 1024, wqsp, 1024, b_qkv, nullptr, nullptr, nullptr, 0, qkv, Qsp,
      Ksp, Khm);
  // K2: z = (scale/16) * Q @ K^T + gumbel(noise)
  gemm_bf16s<2><<<dim3(16, 32), 256, 0, stream>>>(
      Qsp, 1024, Ksp, 1024, nullptr, noise, nullptr, z, NN, nullptr, nullptr,
      nullptr, nullptr);
  // K3: per-row top-16 threshold + mask bits (one wave per row)
  topk_kernel<<<NROWS / 4, 256, 0, stream>>>(z, mask);
  // K4a: per-head softmax denominators (head-major K, kv split x2)
  denom_kernel<<<dim3(64, 16, 2), 256, 0, stream>>>(Qsp, Khm, Zpart);
  // K4b: parallel sparse gather -> attn_out hi/lo split
  gather_kernel<<<dim3(NROWS / 8, NH), 256, 0, stream>>>(qkv, Zpart, mask,
                                                         aosp);
  // K5: out = (attn_out * mean(head_scores)) @ w_proj.T + b_proj
  gemm_bf16s<3><<<dim3(4, 32), 256, 0, stream>>>(
      aosp, 1024, wpsp, 1024, b_proj, nullptr, head_scores, out, NC, nullptr,
      nullptr, nullptr, nullptr);
}